// Round 2
// 485.702 us; speedup vs baseline: 1.1208x; 1.1208x over previous
//
#include <hip/hip_runtime.h>

// ValueNetwork B=8192, rows=97 (1 self + 96 human), HUMAN_DIM=48.
// One block (256 thr) per batch. GEMMs on MFMA 16x16x32 bf16 hi/lo split.
// R6: X stored as 3 column-panels [97][16] ushort. XT planes DELETED:
// step4's B-operand (X^T fragments) is loaded ONCE per block into 24 VGPRs
// via per-lane scalar ds_read_u16 gathers (48/thread, waves 0-2 only; exact
// element addressing — replaces R5's ds_read_b64_tr_b16 whose lane/elem
// semantics failed verification). Staging drops all XT scatter-stores.
// LDS 53,248 -> 33,280 B => 4 blocks/CU (was 3). Pipeline structure (R4's
// 3-barrier strip loop, double-buffered W, exact col-96 rank-1) unchanged.

#define XP (97 * 16)  // ushorts per X column-panel (row stride 16)
#define ES 104        // E plane row stride (ushort), 16B-multiple for b128
#define WS 56         // W (Xw/AX) plane row stride (ushort)

typedef short bf16x8 __attribute__((ext_vector_type(8)));
typedef float f32x4 __attribute__((ext_vector_type(4)));

__device__ __forceinline__ unsigned rtne_hi(float f) {
    unsigned u = __float_as_uint(f);
    return (u + 0x7fffu + ((u >> 16) & 1u)) & 0xffff0000u;
}
__device__ __forceinline__ void split2(float f, unsigned short* h, unsigned short* l) {
    unsigned hb = rtne_hi(f);
    float r = f - __uint_as_float(hb);
    *h = (unsigned short)(hb >> 16);
    *l = (unsigned short)(__float_as_uint(r) >> 16);
}
__device__ __forceinline__ float bf2f(unsigned short u) {
    return __uint_as_float(((unsigned)u) << 16);
}
__device__ __forceinline__ bf16x8 ldf(const unsigned short* p) {
    return *(const bf16x8*)p;
}

__global__ void vnet_prep(const float* __restrict__ w_a, const float* __restrict__ w1,
                          unsigned short* __restrict__ ws) {
    unsigned short* waT_h = ws;                 // waT[c][k] = w_a[k][c], 48x48
    unsigned short* waT_l = ws + 2304;
    unsigned short* w1T_h = ws + 4608;          // w1T[l][j] = w1[j][l], 64x48
    unsigned short* w1T_l = ws + 4608 + 3072;
    for (int i = threadIdx.x; i < 48 * 48; i += blockDim.x) {
        int c = i / 48, k = i % 48;
        unsigned short h, l; split2(w_a[k * 48 + c], &h, &l);
        waT_h[i] = h; waT_l[i] = l;
    }
    for (int i = threadIdx.x; i < 64 * 48; i += blockDim.x) {
        int lo = i / 48, j = i % 48;
        unsigned short h, l; split2(w1[j * 64 + lo], &h, &l);
        w1T_h[i] = h; w1T_l[i] = l;
    }
}

__global__ __launch_bounds__(256, 4)
void vnet_kernel(const float* __restrict__ state,
                 const float* __restrict__ t_w1, const float* __restrict__ t_b1,
                 const float* __restrict__ t_w2, const float* __restrict__ t_b2,
                 const float* __restrict__ w2,   const float* __restrict__ v_w1,
                 const float* __restrict__ v_b1, const float* __restrict__ v_w2,
                 const float* __restrict__ v_b2, const unsigned short* __restrict__ ws,
                 float* __restrict__ out)
{
    __shared__ __align__(16) unsigned short Xh[3 * XP], Xl[3 * XP];       // 9312 B each
    __shared__ __align__(16) unsigned short Eh[16 * ES], El[16 * ES];     // 3328 B each
    __shared__ __align__(16) unsigned short W0h[16 * WS], W0l[16 * WS];   // 1792 B each
    __shared__ __align__(16) unsigned short W1h[16 * WS], W1l[16 * WS];   // 1792 B each
    __shared__ float a0c[112];    // A row 0 numerators->probs; [97..111]=0; head reuses [0..63]
    __shared__ float invb[16];    // per-strip-row 1/sum
    __shared__ float e96[16];     // per-strip-row exp(S[n][96]) (unnormalized)
    __shared__ float pacc[64];    // p accumulator; [0..15] self-state temp at setup

    const unsigned short* waT_h = ws;
    const unsigned short* waT_l = ws + 2304;
    const unsigned short* w1T_h = ws + 4608;
    const unsigned short* w1T_l = ws + 4608 + 3072;

    const int tid  = threadIdx.x;
    const int w    = tid >> 6;
    const int lane = tid & 63;
    const int row  = lane & 15;
    const int quad = lane >> 4;
    const int b    = blockIdx.x;
    const float* sb = state + (size_t)b * (96 * 64);
    const bf16x8 ZF = {0, 0, 0, 0, 0, 0, 0, 0};

    // ---------- stage X rows 1..96 into column panels ----------
    if (tid < 16) pacc[tid] = sb[tid];           // self-state temp
    for (int i = tid; i < 96 * 12; i += 256) {
        int r = i / 12, q = i % 12;
        float4 v = *(const float4*)(sb + r * 64 + 16 + 4 * q);
        unsigned short h0, l0, h1v, l1, h2, l2, h3, l3;
        split2(v.x, &h0, &l0); split2(v.y, &h1v, &l1);
        split2(v.z, &h2, &l2); split2(v.w, &h3, &l3);
        int m = 1 + r;
        int o = (q >> 2) * XP + m * 16 + (q & 3) * 4;
        *(uint2*)&Xh[o] = make_uint2((unsigned)h0 | ((unsigned)h1v << 16),
                                     (unsigned)h2 | ((unsigned)h3 << 16));
        *(uint2*)&Xl[o] = make_uint2((unsigned)l0 | ((unsigned)l1 << 16),
                                     (unsigned)l2 | ((unsigned)l3 << 16));
    }
    __syncthreads();

    // ---------- self MLP ----------
    if (tid < 50) {
        float a = t_b1[tid];
        #pragma unroll
        for (int i = 0; i < 16; ++i) a = fmaf(pacc[i], t_w1[i * 50 + tid], a);
        a0c[tid] = fmaxf(a, 0.f);                // hidden temp
    }
    __syncthreads();
    if (tid < 48) {                              // new_self -> X row0
        float a = t_b2[tid];
        for (int i = 0; i < 50; ++i) a = fmaf(a0c[i], t_w2[i * 48 + tid], a);
        unsigned short h, l; split2(fmaxf(a, 0.f), &h, &l);
        int o = (tid >> 4) * XP + (tid & 15);
        Xh[o] = h; Xl[o] = l;
    }
    if (tid >= 64 && tid < 128) pacc[tid - 64] = 0.f;     // p accumulator
    if (tid >= 128 && tid < 143) a0c[tid - 31] = 0.f;     // a0c[97..111] = 0
    __syncthreads();

    // ---------- step4 B-operand (X^T fragments) -> registers, ONCE ----------
    // Lane (w,quad,row) needs X[32*c3 + 8*quad + j'][16*w + row], j'=0..7:
    // element w*XP + (32*c3 + 8*quad + j')*16 + row in panel layout.
    // Exact per-lane scalar gathers (48 ds_read_u16, once per block).
    bf16x8 B4h[3], B4l[3];
    if (w < 3) {
        #pragma unroll
        for (int c3 = 0; c3 < 3; ++c3) {
            bf16x8 th, tl;
            #pragma unroll
            for (int j = 0; j < 8; ++j) {
                int e = w * XP + (32 * c3 + 8 * quad + j) * 16 + row;
                th[j] = (short)Xh[e];
                tl[j] = (short)Xl[e];
            }
            B4h[c3] = th;
            B4l[c3] = tl;
        }
    } else {
        #pragma unroll
        for (int c3 = 0; c3 < 3; ++c3) { B4h[c3] = ZF; B4l[c3] = ZF; }
    }

    // ---------- prologue: step1(0) -> W0, step2(0) -> E ----------
    {
        if (w < 3) {
            f32x4 acc = {0.f, 0.f, 0.f, 0.f};
            #pragma unroll
            for (int ch = 0; ch < 2; ++ch) {
                int kb = 16 * ch;
                int c = kb + quad * 8;
                int o = (c >> 4) * XP + row * 16 + (c & 15);
                bf16x8 ah = ldf(&Xh[o]);
                bf16x8 al = ldf(&Xl[o]);
                if (ch == 1 && quad < 2) { ah = ZF; al = ZF; }
                bf16x8 bh = ldf(waT_h + (16 * w + row) * 48 + kb + quad * 8);
                bf16x8 bl = ldf(waT_l + (16 * w + row) * 48 + kb + quad * 8);
                acc = __builtin_amdgcn_mfma_f32_16x16x32_bf16(ah, bh, acc, 0, 0, 0);
                acc = __builtin_amdgcn_mfma_f32_16x16x32_bf16(ah, bl, acc, 0, 0, 0);
                acc = __builtin_amdgcn_mfma_f32_16x16x32_bf16(al, bh, acc, 0, 0, 0);
            }
            #pragma unroll
            for (int r = 0; r < 4; ++r) {
                unsigned short h, l; split2(acc[r], &h, &l);
                W0h[(quad * 4 + r) * WS + 16 * w + row] = h;
                W0l[(quad * 4 + r) * WS + 16 * w + row] = l;
            }
        }
    }
    __syncthreads();
    // step2(0): S[n][m] = Xw @ X^T for m in 0..95
    {
        bf16x8 a0h = ldf(&W0h[row * WS + quad * 8]);
        bf16x8 a0l = ldf(&W0l[row * WS + quad * 8]);
        bf16x8 a1h = ldf(&W0h[row * WS + 16 + quad * 8]);
        bf16x8 a1l = ldf(&W0l[row * WS + 16 + quad * 8]);
        if (quad < 2) { a1h = ZF; a1l = ZF; }
        for (int t = w; t < 6; t += 4) {
            int m = 16 * t + row;
            f32x4 acc = {0.f, 0.f, 0.f, 0.f};
            int o0 = (quad >> 1) * XP + m * 16 + (quad & 1) * 8;
            bf16x8 bh = ldf(&Xh[o0]);
            bf16x8 bl = ldf(&Xl[o0]);
            acc = __builtin_amdgcn_mfma_f32_16x16x32_bf16(a0h, bh, acc, 0, 0, 0);
            acc = __builtin_amdgcn_mfma_f32_16x16x32_bf16(a0h, bl, acc, 0, 0, 0);
            acc = __builtin_amdgcn_mfma_f32_16x16x32_bf16(a0l, bh, acc, 0, 0, 0);
            bh = ldf(&Xh[o0 + XP]);
            bl = ldf(&Xl[o0 + XP]);
            acc = __builtin_amdgcn_mfma_f32_16x16x32_bf16(a1h, bh, acc, 0, 0, 0);
            acc = __builtin_amdgcn_mfma_f32_16x16x32_bf16(a1h, bl, acc, 0, 0, 0);
            acc = __builtin_amdgcn_mfma_f32_16x16x32_bf16(a1l, bh, acc, 0, 0, 0);
            #pragma unroll
            for (int r = 0; r < 4; ++r) {
                unsigned short h, l; split2(acc[r], &h, &l);
                Eh[(quad * 4 + r) * ES + m] = h;
                El[(quad * 4 + r) * ES + m] = l;
            }
        }
    }
    __syncthreads();

    // ---------- pipelined strip loop ----------
    for (int s = 0; s < 7; ++s) {
        unsigned short* Wsh = (s & 1) ? W1h : W0h;   // this strip's buffer
        unsigned short* Wsl = (s & 1) ? W1l : W0l;
        unsigned short* Wnh = (s & 1) ? W0h : W1h;   // next strip's buffer
        unsigned short* Wnl = (s & 1) ? W0l : W1l;

        // ---- phase A: step1(s+1) + softmax(s) (incl exact col-96 dot) ----
        if (s < 6 && w < 3) {
            f32x4 acc = {0.f, 0.f, 0.f, 0.f};
            int n = (s + 1) * 16 + row; int nc = n < 97 ? n : 96;  // strip-6 tail
            #pragma unroll
            for (int ch = 0; ch < 2; ++ch) {
                int kb = 16 * ch;
                int c = kb + quad * 8;
                int o = (c >> 4) * XP + nc * 16 + (c & 15);
                bf16x8 ah = ldf(&Xh[o]);
                bf16x8 al = ldf(&Xl[o]);
                if (ch == 1 && quad < 2) { ah = ZF; al = ZF; }
                bf16x8 bh = ldf(waT_h + (16 * w + row) * 48 + kb + quad * 8);
                bf16x8 bl = ldf(waT_l + (16 * w + row) * 48 + kb + quad * 8);
                acc = __builtin_amdgcn_mfma_f32_16x16x32_bf16(ah, bh, acc, 0, 0, 0);
                acc = __builtin_amdgcn_mfma_f32_16x16x32_bf16(ah, bl, acc, 0, 0, 0);
                acc = __builtin_amdgcn_mfma_f32_16x16x32_bf16(al, bh, acc, 0, 0, 0);
            }
            #pragma unroll
            for (int r = 0; r < 4; ++r) {
                unsigned short h, l; split2(acc[r], &h, &l);
                Wnh[(quad * 4 + r) * WS + 16 * w + row] = h;
                Wnl[(quad * 4 + r) * WS + 16 * w + row] = l;
            }
        }
        {   // softmax over 16 rows, 16 lanes each
            int rw = tid >> 4, mg = tid & 15;
            float s96 = 0.f;
            #pragma unroll
            for (int kk = 0; kk < 3; ++kk) {          // S[rw][96] exact fp32 dot
                int c = mg + 16 * kk;
                float xw = bf2f(Wsh[rw * WS + c]) + bf2f(Wsl[rw * WS + c]);
                float xv = bf2f(Xh[kk * XP + 1536 + mg]) + bf2f(Xl[kk * XP + 1536 + mg]);
                s96 = fmaf(xw, xv, s96);
            }
            s96 += __shfl_xor(s96, 1); s96 += __shfl_xor(s96, 2);
            s96 += __shfl_xor(s96, 4); s96 += __shfl_xor(s96, 8);
            float e0 = __expf(s96);
            float sum = (mg == 0) ? e0 : 0.f;
            if (mg == 0) {
                e96[rw] = e0;
                if (s == 0 && rw == 0) a0c[96] = e0;
            }
            for (int m = mg; m < 96; m += 16) {
                int o = rw * ES + m;
                float f = bf2f(Eh[o]) + bf2f(El[o]);
                float e = __expf(f);                  // |S| bounded; no max-sub
                sum += e;
                unsigned short h, l; split2(e, &h, &l);
                Eh[o] = h; El[o] = l;
                if (s == 0 && rw == 0) a0c[m] = e;    // numerators; scaled in phase B
            }
            sum += __shfl_xor(sum, 1); sum += __shfl_xor(sum, 2);
            sum += __shfl_xor(sum, 4); sum += __shfl_xor(sum, 8);
            if (mg == 0) invb[rw] = 1.f / sum;
        }
        __syncthreads();

        // ---- phase B: step4(s): AX = invb*(E@X + e96*X[96]) -> Wsh/Wsl ----
        if (w < 3) {
            f32x4 acc = {0.f, 0.f, 0.f, 0.f};
            #pragma unroll
            for (int c3 = 0; c3 < 3; ++c3) {
                int mb = 32 * c3;
                bf16x8 ah = ldf(&Eh[row * ES + mb + quad * 8]);
                bf16x8 al = ldf(&El[row * ES + mb + quad * 8]);
                acc = __builtin_amdgcn_mfma_f32_16x16x32_bf16(ah, B4h[c3], acc, 0, 0, 0);
                acc = __builtin_amdgcn_mfma_f32_16x16x32_bf16(ah, B4l[c3], acc, 0, 0, 0);
                acc = __builtin_amdgcn_mfma_f32_16x16x32_bf16(al, B4h[c3], acc, 0, 0, 0);
            }
            int j = 16 * w + row;
            float xv = bf2f(Xh[w * XP + 1536 + row]) + bf2f(Xl[w * XP + 1536 + row]);
            #pragma unroll
            for (int r = 0; r < 4; ++r) {
                float v = fmaf(e96[quad * 4 + r], xv, acc[r]) * invb[quad * 4 + r];
                unsigned short h, l; split2(v, &h, &l);
                Wsh[(quad * 4 + r) * WS + j] = h;
                Wsl[(quad * 4 + r) * WS + j] = l;
            }
        } else if (s == 0) {
            float iv0 = invb[0];                      // finalize A row 0
            for (int m = lane; m < 97; m += 64) a0c[m] *= iv0;
        }
        __syncthreads();

        // ---- phase C: step5(s) + step2(s+1) ----
        {   // h1 = relu(AX @ w1); p += a0-weighted rows
            f32x4 acc = {0.f, 0.f, 0.f, 0.f};
            #pragma unroll
            for (int ch = 0; ch < 2; ++ch) {
                int kb = 16 * ch;
                bf16x8 ah = ldf(&Wsh[row * WS + kb + quad * 8]);
                bf16x8 al = ldf(&Wsl[row * WS + kb + quad * 8]);
                if (ch == 1 && quad < 2) { ah = ZF; al = ZF; }
                bf16x8 bh = ldf(w1T_h + (16 * w + row) * 48 + kb + quad * 8);
                bf16x8 bl = ldf(w1T_l + (16 * w + row) * 48 + kb + quad * 8);
                acc = __builtin_amdgcn_mfma_f32_16x16x32_bf16(ah, bh, acc, 0, 0, 0);
                acc = __builtin_amdgcn_mfma_f32_16x16x32_bf16(ah, bl, acc, 0, 0, 0);
                acc = __builtin_amdgcn_mfma_f32_16x16x32_bf16(al, bh, acc, 0, 0, 0);
            }
            float part = 0.f;
            #pragma unroll
            for (int r = 0; r < 4; ++r)
                part += fmaxf(acc[r], 0.f) * a0c[s * 16 + quad * 4 + r];
            part += __shfl_xor(part, 16);
            part += __shfl_xor(part, 32);
            if (quad == 0) pacc[16 * w + row] += part;
        }
        if (s < 6) {   // step2(s+1): S = Xw(next) @ X^T, m in 0..95
            bf16x8 a0h = ldf(&Wnh[row * WS + quad * 8]);
            bf16x8 a0l = ldf(&Wnl[row * WS + quad * 8]);
            bf16x8 a1h = ldf(&Wnh[row * WS + 16 + quad * 8]);
            bf16x8 a1l = ldf(&Wnl[row * WS + 16 + quad * 8]);
            if (quad < 2) { a1h = ZF; a1l = ZF; }
            for (int t = w; t < 6; t += 4) {
                int m = 16 * t + row;
                f32x4 acc = {0.f, 0.f, 0.f, 0.f};
                int o0 = (quad >> 1) * XP + m * 16 + (quad & 1) * 8;
                bf16x8 bh = ldf(&Xh[o0]);
                bf16x8 bl = ldf(&Xl[o0]);
                acc = __builtin_amdgcn_mfma_f32_16x16x32_bf16(a0h, bh, acc, 0, 0, 0);
                acc = __builtin_amdgcn_mfma_f32_16x16x32_bf16(a0h, bl, acc, 0, 0, 0);
                acc = __builtin_amdgcn_mfma_f32_16x16x32_bf16(a0l, bh, acc, 0, 0, 0);
                bh = ldf(&Xh[o0 + XP]);
                bl = ldf(&Xl[o0 + XP]);
                acc = __builtin_amdgcn_mfma_f32_16x16x32_bf16(a1h, bh, acc, 0, 0, 0);
                acc = __builtin_amdgcn_mfma_f32_16x16x32_bf16(a1h, bl, acc, 0, 0, 0);
                acc = __builtin_amdgcn_mfma_f32_16x16x32_bf16(a1l, bh, acc, 0, 0, 0);
                #pragma unroll
                for (int r = 0; r < 4; ++r) {
                    unsigned short h, l; split2(acc[r], &h, &l);
                    Eh[(quad * 4 + r) * ES + m] = h;
                    El[(quad * 4 + r) * ES + m] = l;
                }
            }
        }
        __syncthreads();
    }

    // ---------- head (featb overlaid on a0c; a0c dead) ----------
    float* featb = a0c;
    if (tid < 64) {
        float a = 0.f;
        #pragma unroll 8
        for (int l = 0; l < 64; ++l) a = fmaf(pacc[l], w2[l * 64 + tid], a);
        featb[tid] = fmaxf(a, 0.f);
    }
    __syncthreads();
    if (tid < 64) {
        float a = v_b1[tid];
        #pragma unroll 8
        for (int c = 0; c < 64; ++c) a = fmaf(featb[c], v_w1[c * 64 + tid], a);
        float qd = fmaxf(a, 0.f) * v_w2[tid];
        #pragma unroll
        for (int d = 32; d >= 1; d >>= 1) qd += __shfl_xor(qd, d);
        if (tid == 0) out[b] = qd + v_b2[0];
    }
}

extern "C" void kernel_launch(void* const* d_in, const int* in_sizes, int n_in,
                              void* d_out, int out_size, void* d_ws, size_t ws_size,
                              hipStream_t stream) {
    (void)n_in; (void)ws_size; (void)out_size;
    const float* state = (const float*)d_in[0];
    const float* t_w1  = (const float*)d_in[1];
    const float* t_b1  = (const float*)d_in[2];
    const float* t_w2  = (const float*)d_in[3];
    const float* t_b2  = (const float*)d_in[4];
    const float* w_a   = (const float*)d_in[5];
    const float* w1    = (const float*)d_in[6];
    const float* w2    = (const float*)d_in[7];
    const float* v_w1  = (const float*)d_in[8];
    const float* v_b1  = (const float*)d_in[9];
    const float* v_w2  = (const float*)d_in[10];
    const float* v_b2  = (const float*)d_in[11];
    unsigned short* ws = (unsigned short*)d_ws;
    const int nb = in_sizes[0] / (96 * 64);   // 8192

    vnet_prep<<<1, 256, 0, stream>>>(w_a, w1, ws);
    vnet_kernel<<<nb, 256, 0, stream>>>(state, t_w1, t_b1, t_w2, t_b2, w2,
                                        v_w1, v_b1, v_w2, v_b2, ws, (float*)d_out);
}